// Round 3
// baseline (805.264 us; speedup 1.0000x reference)
//
#include <hip/hip_runtime.h>

// ---------------------------------------------------------------------------
// LabeledConv round 3.
//   out = [Agg0(xb)|..|Agg3(xb)] @ [W'1;..;W'4] + epilogue   (linearity swap)
// R3 changes vs R2:
//   - GEMM BN=256 (full output width): A read once (205 MB, was 410 MB)
//   - aggx: payload software pipeline + nontemporal payload/Agg (L2 kept for xb)
//   - CSR: rank trick (hist atomic returns rank) -> atomic-free fill;
//     dis fused into scan1; cursor array dropped
// ---------------------------------------------------------------------------

typedef __bf16 v8bf __attribute__((ext_vector_type(8)));
typedef float v4f __attribute__((ext_vector_type(4)));

__device__ __forceinline__ unsigned short f2bf(float f) {
  unsigned u = __float_as_uint(f);
  u += 0x7fffu + ((u >> 16) & 1u);  // RNE
  return (unsigned short)(u >> 16);
}
__device__ __forceinline__ float bf2f(unsigned short s) {
  return __uint_as_float(((unsigned)s) << 16);
}
__device__ __forceinline__ void async_ld16(const void* g, void* l) {
  __builtin_amdgcn_global_load_lds((__attribute__((address_space(1))) void*)g,
                                   (__attribute__((address_space(3))) void*)l,
                                   16, 0, 0);
}

// ---------------------------------------------------------------------------
__global__ void lc_zero(int* __restrict__ p, int n) {
  int i = blockIdx.x * 256 + threadIdx.x;
  if (i < n) p[i] = 0;
}

// hist + per-edge rank (atomic return value)
__global__ void lc_hist(const int* __restrict__ e0, const int* __restrict__ e1,
                        const int* __restrict__ e2, const int* __restrict__ e3,
                        int* __restrict__ hist, int* __restrict__ rnk, int N, int E) {
  int e = blockIdx.x * 256 + threadIdx.x;
  if (e >= E) return;
  int k = blockIdx.y;
  const int* ed = (k == 0) ? e0 : (k == 1) ? e1 : (k == 2) ? e2 : e3;
  int col = ed[E + e];
  rnk[(size_t)k * E + e] = atomicAdd(&hist[k * N + col], 1);
}

// exclusive scan part 1 (+ fused dis = rsqrt(deg+1))
__global__ void lc_scan1(const int* __restrict__ in, int* __restrict__ outp,
                         int* __restrict__ bsum, float* __restrict__ dis, int M) {
  __shared__ int tmp[256];
  int t = threadIdx.x, i = blockIdx.x * 256 + t;
  int v = (i < M) ? in[i] : 0;
  if (i < M) dis[i] = rsqrtf((float)(v + 1));
  tmp[t] = v;
  __syncthreads();
  for (int off = 1; off < 256; off <<= 1) {
    int add = (t >= off) ? tmp[t - off] : 0;
    __syncthreads();
    tmp[t] += add;
    __syncthreads();
  }
  if (i < M) outp[i] = tmp[t] - v;
  if (t == 255) bsum[blockIdx.x] = tmp[255];
}

__global__ void lc_scan2(int* __restrict__ bsum, int nb) {
  __shared__ int tmp[256];
  __shared__ int carry_s;
  int t = threadIdx.x;
  if (t == 0) carry_s = 0;
  __syncthreads();
  for (int base = 0; base < nb; base += 256) {
    int i = base + t;
    int v = (i < nb) ? bsum[i] : 0;
    tmp[t] = v;
    __syncthreads();
    for (int off = 1; off < 256; off <<= 1) {
      int add = (t >= off) ? tmp[t - off] : 0;
      __syncthreads();
      tmp[t] += add;
      __syncthreads();
    }
    int carry = carry_s;
    int total = tmp[255];
    if (i < nb) bsum[i] = carry + tmp[t] - v;
    __syncthreads();
    if (t == 0) carry_s = carry + total;
    __syncthreads();
  }
}

__global__ void lc_scan3(int* __restrict__ rp, const int* __restrict__ bsum, int M) {
  int i = blockIdx.x * 256 + threadIdx.x;
  if (i < M) rp[i] += bsum[blockIdx.x];
}

// atomic-free fill using precomputed ranks
__global__ void lc_fill(const int* __restrict__ e0, const int* __restrict__ e1,
                        const int* __restrict__ e2, const int* __restrict__ e3,
                        const int* __restrict__ rp, const int* __restrict__ rnk,
                        const float* __restrict__ dis, int2* __restrict__ payload,
                        int N, int E) {
  int e = blockIdx.x * 256 + threadIdx.x;
  if (e >= E) return;
  int k = blockIdx.y;
  const int* ed = (k == 0) ? e0 : (k == 1) ? e1 : (k == 2) ? e2 : e3;
  int src = ed[e], col = ed[E + e];
  int pos = rp[k * N + col] + rnk[(size_t)k * E + e];
  float nrm = dis[k * N + src] * dis[k * N + col];
  payload[pos] = make_int2(src, __float_as_int(nrm));
}

__global__ void lc_bias(const float* __restrict__ b1, const float* __restrict__ b2,
                        const float* __restrict__ b3, const float* __restrict__ b4,
                        const float* __restrict__ p2, const float* __restrict__ p3,
                        const float* __restrict__ p4, const float* __restrict__ p5,
                        float* __restrict__ biasc) {
  int c = threadIdx.x;
  biasc[c] = b1[c] * p2[c] + b2[c] * p3[c] + b3[c] * p4[c] + b4[c] * p5[c];
}

// Wt[co][k*256+kk] = W_k[kk][co] * p_{k+2}[co]
__global__ void lc_prep(const float* __restrict__ W1, const float* __restrict__ W2,
                        const float* __restrict__ W3, const float* __restrict__ W4,
                        const float* __restrict__ p2, const float* __restrict__ p3,
                        const float* __restrict__ p4, const float* __restrict__ p5,
                        unsigned short* __restrict__ Wt) {
  int b = blockIdx.x;
  int k = b >> 8, co = b & 255;
  int kk = threadIdx.x;
  const float* W = (k == 0) ? W1 : (k == 1) ? W2 : (k == 2) ? W3 : W4;
  const float* p = (k == 0) ? p2 : (k == 1) ? p3 : (k == 2) ? p4 : p5;
  Wt[(size_t)co * 1024 + k * 256 + kk] = f2bf(W[kk * 256 + co] * p[co]);
}

// x -> bf16; m0[n]=t0[n]*x[n,0], m1[n]=t1[n]*x[n,0]
__global__ void lc_cvt(const float4* __restrict__ x4, ushort4* __restrict__ xb4,
                       const float* __restrict__ t0, const float* __restrict__ t1,
                       float* __restrict__ m0, float* __restrict__ m1, int n4) {
  int i = blockIdx.x * 256 + threadIdx.x;
  if (i >= n4) return;
  float4 v = x4[i];
  ushort4 r;
  r.x = f2bf(v.x); r.y = f2bf(v.y); r.z = f2bf(v.z); r.w = f2bf(v.w);
  xb4[i] = r;
  if ((i & 63) == 0) {
    int n = i >> 6;
    float xc = v.x;
    m0[n] = t0[n] * xc;
    m1[n] = t1[n] * xc;
  }
}

// ---------------------------------------------------------------------------
// Aggregate raw xb. 1 wave per (node,k); lane owns 4 channels (8B gather/lane).
// Payload software-pipelined in 4-wide batches; payload/Agg use nontemporal
// accesses so L2 capacity stays with xb.
__global__ __launch_bounds__(256) void lc_aggx(
    const unsigned short* __restrict__ xb, unsigned short* __restrict__ Agg,
    int aggw, int kcount, int kbase, const int* __restrict__ rp,
    const int* __restrict__ hist, const float* __restrict__ dis,
    const long long* __restrict__ payload, int N) {
  int t = threadIdx.x;
  int w = t >> 6, lane = t & 63;
  int n, k, koff;
  if (kcount == 4) { n = blockIdx.x; k = w; koff = k * 256; }
  else { n = blockIdx.x * 4 + w; k = kbase; koff = 0; }
  if (n >= N) return;
  int c = lane * 4;
  int idx = k * N + n;

  float dn = dis[idx];
  float s = dn * dn;  // self-loop norm = 1/deg
  ushort4 hv = *(const ushort4*)&xb[(size_t)n * 256 + c];
  float a0 = bf2f(hv.x) * s, a1 = bf2f(hv.y) * s;
  float a2 = bf2f(hv.z) * s, a3 = bf2f(hv.w) * s;

  int start = rp[idx];
  int cnt = hist[idx];
  int nb4 = cnt >> 2;
  long long pv0, pv1, pv2, pv3;
  if (nb4 > 0) {
    const long long* pp = payload + start;
    pv0 = __builtin_nontemporal_load(pp);
    pv1 = __builtin_nontemporal_load(pp + 1);
    pv2 = __builtin_nontemporal_load(pp + 2);
    pv3 = __builtin_nontemporal_load(pp + 3);
    for (int b = 0; b < nb4; b++) {
      int s0 = (int)pv0, s1 = (int)pv1, s2 = (int)pv2, s3 = (int)pv3;
      float n0 = __int_as_float((int)(pv0 >> 32));
      float n1 = __int_as_float((int)(pv1 >> 32));
      float n2 = __int_as_float((int)(pv2 >> 32));
      float n3 = __int_as_float((int)(pv3 >> 32));
      ushort4 g0 = *(const ushort4*)&xb[(size_t)s0 * 256 + c];
      ushort4 g1 = *(const ushort4*)&xb[(size_t)s1 * 256 + c];
      ushort4 g2 = *(const ushort4*)&xb[(size_t)s2 * 256 + c];
      ushort4 g3 = *(const ushort4*)&xb[(size_t)s3 * 256 + c];
      if (b + 1 < nb4) {  // prefetch next batch while gathers are in flight
        const long long* pn = payload + start + (b + 1) * 4;
        pv0 = __builtin_nontemporal_load(pn);
        pv1 = __builtin_nontemporal_load(pn + 1);
        pv2 = __builtin_nontemporal_load(pn + 2);
        pv3 = __builtin_nontemporal_load(pn + 3);
      }
      a0 += bf2f(g0.x) * n0 + bf2f(g1.x) * n1 + bf2f(g2.x) * n2 + bf2f(g3.x) * n3;
      a1 += bf2f(g0.y) * n0 + bf2f(g1.y) * n1 + bf2f(g2.y) * n2 + bf2f(g3.y) * n3;
      a2 += bf2f(g0.z) * n0 + bf2f(g1.z) * n1 + bf2f(g2.z) * n2 + bf2f(g3.z) * n3;
      a3 += bf2f(g0.w) * n0 + bf2f(g1.w) * n1 + bf2f(g2.w) * n2 + bf2f(g3.w) * n3;
    }
  }
  for (int i = nb4 << 2; i < cnt; i++) {
    long long pv = __builtin_nontemporal_load(payload + start + i);
    int src = (int)pv;
    float nr = __int_as_float((int)(pv >> 32));
    ushort4 g = *(const ushort4*)&xb[(size_t)src * 256 + c];
    a0 += bf2f(g.x) * nr; a1 += bf2f(g.y) * nr;
    a2 += bf2f(g.z) * nr; a3 += bf2f(g.w) * nr;
  }
  ushort4 r;
  r.x = f2bf(a0); r.y = f2bf(a1); r.z = f2bf(a2); r.w = f2bf(a3);
  __builtin_nontemporal_store(*(const long long*)&r,
                              (long long*)&Agg[(size_t)n * aggw + koff + c]);
}

// ---------------------------------------------------------------------------
// GEMM: out[M x 256] (+)= A[M x K]bf16 @ B^T[256 x K]bf16 + fused epilogue.
// BM=128, BN=256 (full width -> A read once), BK=32, 4 waves (2x2 of 64x128).
__global__ __launch_bounds__(256) void lc_gemm(
    const unsigned short* __restrict__ A, int strideA,
    const unsigned short* __restrict__ B, int strideB, int K,
    float* __restrict__ out, int Mrows, int addprev, int doepi,
    const float* __restrict__ m0, const float* __restrict__ m1,
    const float* __restrict__ p0, const float* __restrict__ p1,
    const float* __restrict__ biasc) {
  __shared__ alignas(16) unsigned short As[128 * 32];
  __shared__ alignas(16) unsigned short Bs[256 * 32];
  int t = threadIdx.x;
  int w = t >> 6, lane = t & 63;
  int wm = w & 1, wn = w >> 1;
  int quad = lane >> 4, l16 = lane & 15;
  int row0 = blockIdx.x * 128;

  v4f acc[4][8];
#pragma unroll
  for (int mt = 0; mt < 4; mt++)
#pragma unroll
    for (int nt = 0; nt < 8; nt++) {
      v4f z = {0.f, 0.f, 0.f, 0.f};
      acc[mt][nt] = z;
    }

  for (int kk = 0; kk < K; kk += 32) {
#pragma unroll
    for (int p = 0; p < 2; p++) {  // A: 512 chunks of 16B
      int cbase = p * 256 + w * 64;
      int cA = cbase + lane;
      int rl = cA >> 2, c16 = cA & 3;
      int grow = row0 + rl;
      if (grow >= Mrows) grow = Mrows - 1;  // clamp tail; stores guarded
      async_ld16(A + (size_t)grow * strideA + kk + c16 * 8, &As[cbase * 8]);
    }
#pragma unroll
    for (int p = 0; p < 4; p++) {  // B: 1024 chunks of 16B
      int cbase = p * 256 + w * 64;
      int cB = cbase + lane;
      int rl = cB >> 2, c16 = cB & 3;
      async_ld16(B + (size_t)rl * strideB + kk + c16 * 8, &Bs[cbase * 8]);
    }
    __syncthreads();

    v8bf af[4];
#pragma unroll
    for (int mt = 0; mt < 4; mt++) {
      int r = wm * 64 + mt * 16 + l16;
      af[mt] = *(const v8bf*)&As[r * 32 + quad * 8];
    }
#pragma unroll
    for (int nt = 0; nt < 8; nt++) {
      int nr = wn * 128 + nt * 16 + l16;
      v8bf bfr = *(const v8bf*)&Bs[nr * 32 + quad * 8];
#pragma unroll
      for (int mt = 0; mt < 4; mt++)
        acc[mt][nt] =
            __builtin_amdgcn_mfma_f32_16x16x32_bf16(af[mt], bfr, acc[mt][nt], 0, 0, 0);
    }
    __syncthreads();
  }

  // epilogue: C/D layout col=lane&15, row=quad*4+reg
  float pc0[8], pc1[8], bc[8];
#pragma unroll
  for (int nt = 0; nt < 8; nt++) {
    int gcol = wn * 128 + nt * 16 + l16;
    pc0[nt] = doepi ? p0[gcol] : 0.f;
    pc1[nt] = doepi ? p1[gcol] : 0.f;
    bc[nt] = doepi ? biasc[gcol] : 0.f;
  }
#pragma unroll
  for (int mt = 0; mt < 4; mt++)
#pragma unroll
    for (int r = 0; r < 4; r++) {
      int grow = row0 + wm * 64 + mt * 16 + quad * 4 + r;
      if (grow >= Mrows) continue;
      float m0v = 0.f, m1v = 0.f;
      if (doepi) { m0v = m0[grow]; m1v = m1[grow]; }
#pragma unroll
      for (int nt = 0; nt < 8; nt++) {
        int gcol = wn * 128 + nt * 16 + l16;
        size_t o = (size_t)grow * 256 + gcol;
        float v = acc[mt][nt][r];
        if (addprev) v += out[o];
        if (doepi) v += m0v * pc0[nt] + m1v * pc1[nt] + bc[nt];
        out[o] = v;
      }
    }
}

// ---------------------------------------------------------------------------
extern "C" void kernel_launch(void* const* d_in, const int* in_sizes, int n_in,
                              void* d_out, int out_size, void* d_ws, size_t ws_size,
                              hipStream_t stream) {
  const float* x = (const float*)d_in[0];
  const int* e00 = (const int*)d_in[1];
  const int* e01 = (const int*)d_in[2];
  const int* e10 = (const int*)d_in[3];
  const int* e11 = (const int*)d_in[4];
  const float* t0 = (const float*)d_in[5];
  const float* t1 = (const float*)d_in[6];
  const float* W1 = (const float*)d_in[7];
  const float* b1 = (const float*)d_in[8];
  const float* W2 = (const float*)d_in[9];
  const float* b2 = (const float*)d_in[10];
  const float* W3 = (const float*)d_in[11];
  const float* b3 = (const float*)d_in[12];
  const float* W4 = (const float*)d_in[13];
  const float* b4 = (const float*)d_in[14];
  const float* p0 = (const float*)d_in[15];
  const float* p1 = (const float*)d_in[16];
  const float* p2 = (const float*)d_in[17];
  const float* p3 = (const float*)d_in[18];
  const float* p4 = (const float*)d_in[19];
  const float* p5 = (const float*)d_in[20];
  float* out = (float*)d_out;

  int N = in_sizes[0] / 256;
  int E = in_sizes[1] / 2;
  int M4 = 4 * N;
  int nb = (M4 + 255) / 256;

  char* wp = (char*)d_ws;
  auto carve = [&](size_t bytes) {
    void* r = (void*)wp;
    wp += (bytes + 255) & ~(size_t)255;
    return r;
  };
  unsigned short* xb = (unsigned short*)carve((size_t)N * 256 * 2);
  unsigned short* Wt = (unsigned short*)carve((size_t)256 * 1024 * 2);
  int* hist = (int*)carve((size_t)M4 * 4);
  float* dis = (float*)carve((size_t)M4 * 4);
  int* rp = (int*)carve((size_t)M4 * 4);
  int* rnk = (int*)carve((size_t)4 * E * 4);
  int* bsum = (int*)carve((size_t)nb * 4);
  float* biasc = (float*)carve(256 * 4);
  float* m0 = (float*)carve((size_t)N * 4);
  float* m1 = (float*)carve((size_t)N * 4);
  int2* payload = (int2*)carve((size_t)4 * E * 8);
  size_t used = (size_t)(wp - (char*)d_ws);
  size_t remain = (ws_size > used) ? ws_size - used : 0;
  bool fat = remain >= (size_t)N * 1024 * 2;
  unsigned short* Agg = (unsigned short*)wp;  // fat: N x 1024; lean: N x 256

  int gE = (E + 255) / 256;
  int gM = (M4 + 255) / 256;

  lc_zero<<<gM, 256, 0, stream>>>(hist, M4);
  lc_hist<<<dim3(gE, 4), 256, 0, stream>>>(e00, e01, e10, e11, hist, rnk, N, E);
  lc_scan1<<<nb, 256, 0, stream>>>(hist, rp, bsum, dis, M4);
  lc_scan2<<<1, 256, 0, stream>>>(bsum, nb);
  lc_scan3<<<nb, 256, 0, stream>>>(rp, bsum, M4);
  lc_fill<<<dim3(gE, 4), 256, 0, stream>>>(e00, e01, e10, e11, rp, rnk, dis,
                                           payload, N, E);
  lc_bias<<<1, 256, 0, stream>>>(b1, b2, b3, b4, p2, p3, p4, p5, biasc);
  lc_prep<<<1024, 256, 0, stream>>>(W1, W2, W3, W4, p2, p3, p4, p5, Wt);
  lc_cvt<<<(N * 64 + 255) / 256, 256, 0, stream>>>((const float4*)x, (ushort4*)xb,
                                                   t0, t1, m0, m1, N * 64);

  int gemm_mb = (N + 127) / 128;
  if (fat) {
    lc_aggx<<<N, 256, 0, stream>>>(xb, Agg, 1024, 4, 0, rp, hist, dis,
                                   (const long long*)payload, N);
    lc_gemm<<<gemm_mb, 256, 0, stream>>>(Agg, 1024, Wt, 1024, 1024, out, N, 0, 1,
                                         m0, m1, p0, p1, biasc);
  } else {
    for (int k = 0; k < 4; k++) {
      lc_aggx<<<(N + 3) / 4, 256, 0, stream>>>(xb, Agg, 256, 1, k, rp, hist, dis,
                                               (const long long*)payload, N);
      lc_gemm<<<gemm_mb, 256, 0, stream>>>(Agg, 256, Wt + k * 256, 1024, 256, out, N,
                                           (k > 0) ? 1 : 0, (k == 3) ? 1 : 0, m0, m1,
                                           p0, p1, biasc);
    }
  }
}